// Round 6
// baseline (1589.139 us; speedup 1.0000x reference)
//
#include <hip/hip_runtime.h>
#include <hip/hip_bf16.h>
#include <math.h>

#define NEG_SLOPE 0.2f
#define NPB 32          // nodes per bucket
#define MAXNB 1600      // LDS histogram capacity (NB = ceil(50000/32) = 1563)
#define BIN_CHUNK 8192  // edges per k_bin block

__device__ __forceinline__ unsigned f2bf(float f) {
  unsigned u = __float_as_uint(f);
  return (u + 0x7fffu + ((u >> 16) & 1u)) >> 16;  // RNE
}

// ---------------------------------------------------------------------------
// K1: h = x @ W + b_W (registers), emit:
//   hb [N][64] uint : {bf16 h(head0,d) lo | bf16 h(head1,d) hi}
//   ai [N][2], aj [N][2] : per-node attention scalars
// ---------------------------------------------------------------------------
__global__ __launch_bounds__(128) void k1_gemm(
    const float* __restrict__ x, const float* __restrict__ W,
    const float* __restrict__ bW, const float* __restrict__ att,
    unsigned int* __restrict__ hb, float* __restrict__ ai,
    float* __restrict__ aj, int Nn) {
  __shared__ float Ws[64 * 128];
  __shared__ float xs[64];
  __shared__ float bs[128];
  __shared__ float atts[256];
  __shared__ float hsh[128];
  int t = threadIdx.x;
  for (int i = t; i < 64 * 128; i += 128) Ws[i] = W[i];
  bs[t] = bW[t];
  atts[t] = att[t];
  atts[128 + t] = att[128 + t];
  __syncthreads();
  int head = t >> 6;
  int lane = t & 63;
  for (int row = blockIdx.x; row < Nn; row += gridDim.x) {
    if (t < 64) xs[t] = x[(size_t)row * 64 + t];
    __syncthreads();
    float acc = bs[t];
#pragma unroll
    for (int k = 0; k < 64; ++k) acc += xs[k] * Ws[k * 128 + t];
    hsh[t] = acc;
    float ti = atts[head * 128 + lane] * acc;
    float tj = atts[head * 128 + 64 + lane] * acc;
#pragma unroll
    for (int off = 32; off > 0; off >>= 1) {
      ti += __shfl_down(ti, off, 64);
      tj += __shfl_down(tj, off, 64);
    }
    if (lane == 0) { ai[row * 2 + head] = ti; aj[row * 2 + head] = tj; }
    __syncthreads();
    if (t < 64)
      hb[(size_t)row * 64 + t] = f2bf(hsh[t]) | (f2bf(hsh[64 + t]) << 16);
  }
}

// ---------------------------------------------------------------------------
// K_degb: per-bucket edge counts (LDS pre-aggregated histogram).
// ---------------------------------------------------------------------------
__global__ __launch_bounds__(256) void k_degb(
    const int* __restrict__ ei, int* __restrict__ bcnt, int Ee, int NB) {
  __shared__ int hist[MAXNB];
  int t = threadIdx.x;
  for (int i = t; i < NB; i += 256) hist[i] = 0;
  __syncthreads();
  int stride = gridDim.x * 256;
  for (int e = blockIdx.x * 256 + t; e < Ee; e += stride)
    atomicAdd(&hist[ei[Ee + e] >> 5], 1);
  __syncthreads();
  for (int i = t; i < NB; i += 256)
    if (hist[i]) atomicAdd(&bcnt[i], hist[i]);
}

// ---------------------------------------------------------------------------
// K_scanb: single-block exclusive scan over NB bucket counts ->
// bucketbase[NB+1] and gcursor[NB] (running allocation cursor).
// ---------------------------------------------------------------------------
__global__ __launch_bounds__(256) void k_scanb(
    const int* __restrict__ bcnt, int* __restrict__ bucketbase,
    int* __restrict__ gcursor, int NB, int Ee) {
  __shared__ int s[256];
  int t = threadIdx.x;
  int per = (NB + 255) / 256;
  int local[8];
  int sum = 0;
  for (int j = 0; j < per; ++j) {
    int b = t * per + j;
    int v = (b < NB) ? bcnt[b] : 0;
    local[j] = sum;
    sum += v;
  }
  s[t] = sum;
  __syncthreads();
#pragma unroll
  for (int o = 1; o < 256; o <<= 1) {
    int xv = (t >= o) ? s[t - o] : 0;
    __syncthreads();
    s[t] += xv;
    __syncthreads();
  }
  int excl = s[t] - sum;
  for (int j = 0; j < per; ++j) {
    int b = t * per + j;
    if (b < NB) {
      int base = excl + local[j];
      bucketbase[b] = base;
      gcursor[b] = base;
    }
  }
  if (t == 0) bucketbase[NB] = Ee;
}

// ---------------------------------------------------------------------------
// K_bin: per-block LDS histogram -> per-(block,bucket) global reservation ->
// clustered record writes {src:17 | dl:5<<17 | a0<<22 | a1<<25 | a2<<28}.
// Also computes softmax denominators sden[src][h] (global f32 atomics).
// ---------------------------------------------------------------------------
__global__ __launch_bounds__(256) void k_bin(
    const int* __restrict__ ei, const int* __restrict__ eattr,
    const float* __restrict__ att, const float* __restrict__ bemb,
    const float* __restrict__ ai, const float* __restrict__ aj,
    float* __restrict__ sden, int* __restrict__ gcursor,
    unsigned int* __restrict__ rec, int Ee, int NB) {
  __shared__ int hist[MAXNB];
  __shared__ float tbl[30];
  int t = threadIdx.x;
  if (t < 30) {
    int f = t / 10, rem = t % 10, c = rem >> 1, hh = rem & 1;
    float sacc = 0.f;
    for (int d = 0; d < 64; ++d)
      sacc += att[hh * 128 + 64 + d] * bemb[(f * 5 + c) * 128 + hh * 64 + d];
    tbl[t] = sacc;
  }
  for (int i = t; i < NB; i += 256) hist[i] = 0;
  __syncthreads();
  int start = blockIdx.x * BIN_CHUNK;
  int end = min(start + BIN_CHUNK, Ee);
  // pass A: local histogram
  for (int e = start + t; e < end; e += 256)
    atomicAdd(&hist[ei[Ee + e] >> 5], 1);
  __syncthreads();
  // reserve: hist[b] becomes this block's global write cursor for bucket b
  for (int b = t; b < NB; b += 256) {
    int c = hist[b];
    if (c) hist[b] = atomicAdd(&gcursor[b], c);
  }
  __syncthreads();
  // pass B: write records (clustered) + softmax denominators
  for (int e = start + t; e < end; e += 256) {
    int dst = ei[Ee + e];
    int src = ei[e];
    int a0 = eattr[e * 3], a1 = eattr[e * 3 + 1], a2 = eattr[e * 3 + 2];
    int b = dst >> 5, dl = dst & 31;
    int pos = atomicAdd(&hist[b], 1);
    rec[pos] = (unsigned)src | ((unsigned)dl << 17) | ((unsigned)a0 << 22) |
               ((unsigned)a1 << 25) | ((unsigned)a2 << 28);
    float lg0 = ai[dst * 2] + aj[src * 2] + tbl[a0 * 2] + tbl[10 + a1 * 2] +
                tbl[20 + a2 * 2];
    float lg1 = ai[dst * 2 + 1] + aj[src * 2 + 1] + tbl[a0 * 2 + 1] +
                tbl[10 + a1 * 2 + 1] + tbl[20 + a2 * 2 + 1];
    lg0 = lg0 >= 0.f ? lg0 : NEG_SLOPE * lg0;
    lg1 = lg1 >= 0.f ? lg1 : NEG_SLOPE * lg1;
    atomicAdd(&sden[src * 2], __expf(lg0));
    atomicAdd(&sden[src * 2 + 1], __expf(lg1));
  }
}

// ---------------------------------------------------------------------------
// K_gather: one block per bucket (32 nodes). Aggregators in LDS (ds_add_f32),
// sequential record reads, 4-deep unrolled random hb gathers, coalesced
// epilogue (head-mean + bias).
// ---------------------------------------------------------------------------
__global__ __launch_bounds__(256) void k_gather(
    const unsigned int* __restrict__ rec, const int* __restrict__ bucketbase,
    const float2* __restrict__ aj2, const float2* __restrict__ sd2,
    const float2* __restrict__ ai2, const unsigned int* __restrict__ hb,
    const float* __restrict__ bemb, const float* __restrict__ att,
    const float* __restrict__ bias, float* __restrict__ out, int Nn) {
  __shared__ float aggr[NPB * 128];   // 16 KB
  __shared__ float t01s[25 * 128];    // 12.5 KB: bemb0[a0]+bemb1[a1]
  __shared__ float b2s[5 * 128];      // 2.5 KB
  __shared__ float tbl[30];
  __shared__ float ais[NPB * 2];
  int t = threadIdx.x;
  if (t < 30) {
    int f = t / 10, rem = t % 10, c = rem >> 1, hh = rem & 1;
    float sacc = 0.f;
    for (int d = 0; d < 64; ++d)
      sacc += att[hh * 128 + 64 + d] * bemb[(f * 5 + c) * 128 + hh * 64 + d];
    tbl[t] = sacc;
  }
  for (int i = t; i < 25 * 128; i += 256) {
    int c01 = i >> 7, d = i & 127;
    t01s[i] = bemb[(c01 / 5) * 128 + d] + bemb[640 + (c01 % 5) * 128 + d];
  }
  for (int i = t; i < 5 * 128; i += 256) b2s[i] = bemb[1280 + i];
  for (int i = t; i < NPB * 128; i += 256) aggr[i] = 0.f;
  int node0 = blockIdx.x * NPB;
  if (t < NPB && node0 + t < Nn) {
    float2 v = ai2[node0 + t];
    ais[t * 2] = v.x;
    ais[t * 2 + 1] = v.y;
  }
  __syncthreads();
  int wave = t >> 6;
  int lane = t & 63;
  int p0 = bucketbase[blockIdx.x], p1 = bucketbase[blockIdx.x + 1];

#define EDGE_BODY(U, HV, AJV, SDV)                                              \
  {                                                                             \
    int dl = (U >> 17) & 31;                                                    \
    int a0 = (U >> 22) & 7, a1 = (U >> 25) & 7, a2 = (U >> 28) & 7;             \
    float lg0 = ais[dl * 2] + AJV.x + tbl[a0 * 2] + tbl[10 + a1 * 2] +          \
                tbl[20 + a2 * 2];                                               \
    float lg1 = ais[dl * 2 + 1] + AJV.y + tbl[a0 * 2 + 1] +                     \
                tbl[10 + a1 * 2 + 1] + tbl[20 + a2 * 2 + 1];                    \
    lg0 = lg0 >= 0.f ? lg0 : NEG_SLOPE * lg0;                                   \
    lg1 = lg1 >= 0.f ? lg1 : NEG_SLOPE * lg1;                                   \
    float al0 = __expf(lg0) / (SDV.x + 1e-16f);                                 \
    float al1 = __expf(lg1) / (SDV.y + 1e-16f);                                 \
    int bp = (a0 * 5 + a1) * 128, b2 = a2 * 128;                                \
    float e0 = t01s[bp + lane] + b2s[b2 + lane];                                \
    float e1 = t01s[bp + 64 + lane] + b2s[b2 + 64 + lane];                      \
    float m0 = al0 * (__uint_as_float(HV << 16) + e0);                          \
    float m1 = al1 * (__uint_as_float(HV & 0xffff0000u) + e1);                  \
    atomicAdd(&aggr[dl * 128 + lane], m0);                                      \
    atomicAdd(&aggr[dl * 128 + 64 + lane], m1);                                 \
  }

  int p = p0 + wave;
  for (; p + 12 < p1; p += 16) {
    unsigned u0 = rec[p], u1 = rec[p + 4], u2 = rec[p + 8], u3 = rec[p + 12];
    int r0 = u0 & 0x1FFFF, r1 = u1 & 0x1FFFF, r2 = u2 & 0x1FFFF, r3 = u3 & 0x1FFFF;
    unsigned hv0 = hb[(size_t)r0 * 64 + lane];
    unsigned hv1 = hb[(size_t)r1 * 64 + lane];
    unsigned hv2 = hb[(size_t)r2 * 64 + lane];
    unsigned hv3 = hb[(size_t)r3 * 64 + lane];
    float2 ajv0 = aj2[r0], ajv1 = aj2[r1], ajv2 = aj2[r2], ajv3 = aj2[r3];
    float2 sdv0 = sd2[r0], sdv1 = sd2[r1], sdv2 = sd2[r2], sdv3 = sd2[r3];
    EDGE_BODY(u0, hv0, ajv0, sdv0)
    EDGE_BODY(u1, hv1, ajv1, sdv1)
    EDGE_BODY(u2, hv2, ajv2, sdv2)
    EDGE_BODY(u3, hv3, ajv3, sdv3)
  }
  for (; p < p1; p += 4) {
    unsigned u0 = rec[p];
    int r0 = u0 & 0x1FFFF;
    unsigned hv0 = hb[(size_t)r0 * 64 + lane];
    float2 ajv0 = aj2[r0];
    float2 sdv0 = sd2[r0];
    EDGE_BODY(u0, hv0, ajv0, sdv0)
  }
#undef EDGE_BODY
  __syncthreads();
  for (int i = t; i < NPB * 64; i += 256) {
    int dl = i >> 6, d = i & 63;
    int n = node0 + dl;
    if (n < Nn)
      out[(size_t)n * 64 + d] =
          0.5f * (aggr[dl * 128 + d] + aggr[dl * 128 + 64 + d]) + bias[d];
  }
}

extern "C" void kernel_launch(void* const* d_in, const int* in_sizes, int n_in,
                              void* d_out, int out_size, void* d_ws, size_t ws_size,
                              hipStream_t stream) {
  const float* x    = (const float*)d_in[0];
  const int*   ei   = (const int*)d_in[1];
  const int*   eatt = (const int*)d_in[2];
  const float* W    = (const float*)d_in[3];
  const float* bW   = (const float*)d_in[4];
  const float* att  = (const float*)d_in[5];
  const float* bias = (const float*)d_in[6];
  const float* bemb = (const float*)d_in[7];
  int Nn = in_sizes[0] / 64;
  int Ee = in_sizes[1] / 2;
  int NB = (Nn + NPB - 1) / NPB;

  char* ws = (char*)d_ws;
  ws = (char*)(((uintptr_t)ws + 15) & ~(uintptr_t)15);
  float* aj = (float*)ws;          ws += (size_t)Nn * 2 * 4;
  float* sden = (float*)ws;        ws += (size_t)Nn * 2 * 4;
  float* ai = (float*)ws;          ws += (size_t)Nn * 2 * 4;
  unsigned int* hb = (unsigned int*)ws; ws += (size_t)Nn * 64 * 4;
  int* bcnt = (int*)ws;            ws += (size_t)NB * 4;
  int* bucketbase = (int*)ws;      ws += (size_t)(NB + 1) * 4;
  int* gcursor = (int*)ws;         ws += (size_t)NB * 4;
  unsigned int* rec = (unsigned int*)ws; ws += (size_t)Ee * 4;

  hipMemsetAsync(sden, 0, (size_t)Nn * 2 * 4, stream);
  hipMemsetAsync(bcnt, 0, (size_t)NB * 4, stream);

  k1_gemm<<<1024, 128, 0, stream>>>(x, W, bW, att, hb, ai, aj, Nn);
  k_degb<<<512, 256, 0, stream>>>(ei, bcnt, Ee, NB);
  k_scanb<<<1, 256, 0, stream>>>(bcnt, bucketbase, gcursor, NB, Ee);
  k_bin<<<(Ee + BIN_CHUNK - 1) / BIN_CHUNK, 256, 0, stream>>>(
      ei, eatt, att, bemb, ai, aj, sden, gcursor, rec, Ee, NB);
  k_gather<<<NB, 256, 0, stream>>>(rec, bucketbase, (const float2*)aj,
                                   (const float2*)sden, (const float2*)ai, hb,
                                   bemb, att, bias, (float*)d_out, Nn);
}

// Round 7
// 737.637 us; speedup vs baseline: 2.1544x; 2.1544x over previous
//
#include <hip/hip_runtime.h>
#include <hip/hip_bf16.h>
#include <math.h>

#define NEG_SLOPE 0.2f

__device__ __forceinline__ unsigned f2bf(float f) {
  unsigned u = __float_as_uint(f);
  return (u + 0x7fffu + ((u >> 16) & 1u)) >> 16;  // RNE
}

// ---------------------------------------------------------------------------
// K1: h = x @ W + b_W (registers), emit:
//   hb  [N][64] uint : {bf16 h(head0,d) lo | bf16 h(head1,d) hi}
//   ai  [N][2]       : dot(att_i[hh], h[n,hh])
//   aj  [N][2]       : dot(att_j[hh], h[n,hh])
// ---------------------------------------------------------------------------
__global__ __launch_bounds__(128) void k1_gemm(
    const float* __restrict__ x, const float* __restrict__ W,
    const float* __restrict__ bW, const float* __restrict__ att,
    unsigned int* __restrict__ hb, float* __restrict__ ai,
    float* __restrict__ aj, int Nn) {
  __shared__ float Ws[64 * 128];
  __shared__ float xs[64];
  __shared__ float bs[128];
  __shared__ float atts[256];
  __shared__ float hsh[128];
  int t = threadIdx.x;  // 0..127
  for (int i = t; i < 64 * 128; i += 128) Ws[i] = W[i];
  bs[t] = bW[t];
  atts[t] = att[t];
  atts[128 + t] = att[128 + t];
  __syncthreads();
  int head = t >> 6;
  int lane = t & 63;
  for (int row = blockIdx.x; row < Nn; row += gridDim.x) {
    if (t < 64) xs[t] = x[(size_t)row * 64 + t];
    __syncthreads();
    float acc = bs[t];
#pragma unroll
    for (int k = 0; k < 64; ++k) acc += xs[k] * Ws[k * 128 + t];
    hsh[t] = acc;
    float ti = atts[head * 128 + lane] * acc;
    float tj = atts[head * 128 + 64 + lane] * acc;
#pragma unroll
    for (int off = 32; off > 0; off >>= 1) {
      ti += __shfl_down(ti, off, 64);
      tj += __shfl_down(tj, off, 64);
    }
    if (lane == 0) { ai[row * 2 + head] = ti; aj[row * 2 + head] = tj; }
    __syncthreads();
    if (t < 64)  // coalesced packed store: one dword per lane
      hb[(size_t)row * 64 + t] = f2bf(hsh[t]) | (f2bf(hsh[64 + t]) << 16);
  }
}

// ---------------------------------------------------------------------------
// CSR build by DESTINATION: histogram -> exclusive scan -> fill.
// ---------------------------------------------------------------------------
__global__ __launch_bounds__(256) void k_deg(
    const int* __restrict__ ei, int* __restrict__ deg, int Ee) {
  int e = blockIdx.x * blockDim.x + threadIdx.x;
  if (e < Ee) atomicAdd(&deg[ei[Ee + e]], 1);
}

__global__ __launch_bounds__(256) void k_scan1(
    const int* __restrict__ deg, int* __restrict__ off, int* __restrict__ bsum, int Nn) {
  __shared__ int s[256];
  int t = threadIdx.x;
  int i = blockIdx.x * 256 + t;
  int v = (i < Nn) ? deg[i] : 0;
  s[t] = v;
  __syncthreads();
#pragma unroll
  for (int o = 1; o < 256; o <<= 1) {
    int xv = (t >= o) ? s[t - o] : 0;
    __syncthreads();
    s[t] += xv;
    __syncthreads();
  }
  if (i < Nn) off[i] = s[t] - v;
  if (t == 255) bsum[blockIdx.x] = s[t];
}

__global__ __launch_bounds__(256) void k_scan2(
    int* __restrict__ bsum, int* __restrict__ bpre, int nb) {
  __shared__ int s[256];
  int t = threadIdx.x;
  int v = (t < nb) ? bsum[t] : 0;
  s[t] = v;
  __syncthreads();
#pragma unroll
  for (int o = 1; o < 256; o <<= 1) {
    int xv = (t >= o) ? s[t - o] : 0;
    __syncthreads();
    s[t] += xv;
    __syncthreads();
  }
  if (t < nb) bpre[t] = s[t] - v;
}

__global__ __launch_bounds__(256) void k_scan3(
    int* __restrict__ off, const int* __restrict__ bpre, int Nn, int Ee) {
  int i = blockIdx.x * 256 + threadIdx.x;
  if (i < Nn) off[i] += bpre[blockIdx.x];
  if (i == 0) off[Nn] = Ee;
}

// ---------------------------------------------------------------------------
// K_fill: softmax denominators (atomic) + 4-byte CSR record scatter via
// atomicExch — atomics write only their 4 B payload downstream (measured r2:
// WRITE_SIZE == exact atomic payload), vs 128 B/line for plain scattered
// stores (measured r3/r5: 202 MB for 1.6M dword stores).
// Record: {src:17b | a0<<17 | a1<<20 | a2<<23}.
// ---------------------------------------------------------------------------
__global__ __launch_bounds__(256) void k_fill(
    const int* __restrict__ ei, const int* __restrict__ eattr,
    const float* __restrict__ att, const float* __restrict__ bemb,
    const float* __restrict__ ai, const float* __restrict__ aj,
    float* __restrict__ sden, const int* __restrict__ off,
    int* __restrict__ wcur, unsigned int* __restrict__ eix, int Ee) {
  __shared__ float tbl[30];  // [f][c][hh] = f*10 + c*2 + hh
  int t = threadIdx.x;
  if (t < 30) {
    int f = t / 10, rem = t % 10, c = rem >> 1, hh = rem & 1;
    float sacc = 0.f;
    for (int d = 0; d < 64; ++d)
      sacc += att[hh * 128 + 64 + d] * bemb[(f * 5 + c) * 128 + hh * 64 + d];
    tbl[t] = sacc;
  }
  __syncthreads();
  int e = blockIdx.x * blockDim.x + t;
  if (e >= Ee) return;
  int r = ei[e], c = ei[Ee + e];
  int a0 = eattr[e * 3], a1 = eattr[e * 3 + 1], a2 = eattr[e * 3 + 2];
  float lg0 = ai[c * 2] + aj[r * 2] + tbl[a0 * 2] + tbl[10 + a1 * 2] + tbl[20 + a2 * 2];
  float lg1 = ai[c * 2 + 1] + aj[r * 2 + 1] + tbl[a0 * 2 + 1] + tbl[10 + a1 * 2 + 1] +
              tbl[20 + a2 * 2 + 1];
  lg0 = lg0 >= 0.f ? lg0 : NEG_SLOPE * lg0;
  lg1 = lg1 >= 0.f ? lg1 : NEG_SLOPE * lg1;
  atomicAdd(&sden[r * 2], __expf(lg0));
  atomicAdd(&sden[r * 2 + 1], __expf(lg1));
  int pos = off[c] + atomicAdd(&wcur[c], 1);
  unsigned rec = (unsigned)r | ((unsigned)a0 << 17) | ((unsigned)a1 << 20) |
                 ((unsigned)a2 << 23);
  atomicExch(&eix[pos], rec);  // 4 B downstream write instead of 128 B line
}

// ---------------------------------------------------------------------------
// K_gather: one wave per dst node, lane = d; 4-way unrolled edge loop with
// batched independent loads (4 hb gathers + 4 aj + 4 sden in flight).
// Edge-emb via pair-combined LDS table (4 LDS reads/edge instead of 6).
// ---------------------------------------------------------------------------
__global__ __launch_bounds__(256) void k_gather(
    const unsigned int* __restrict__ eix, const int* __restrict__ off,
    const float2* __restrict__ aj2, const float2* __restrict__ sd2,
    const float* __restrict__ ai, const unsigned int* __restrict__ hb,
    const float* __restrict__ bemb, const float* __restrict__ att,
    const float* __restrict__ bias, float* __restrict__ out, int Nn) {
  __shared__ float t01s[25 * 128];  // bemb0[a0]+bemb1[a1] pair table
  __shared__ float b2s[5 * 128];
  __shared__ float tbl[30];
  int t = threadIdx.x;
  if (t < 30) {
    int f = t / 10, rem = t % 10, c = rem >> 1, hh = rem & 1;
    float sacc = 0.f;
    for (int d = 0; d < 64; ++d)
      sacc += att[hh * 128 + 64 + d] * bemb[(f * 5 + c) * 128 + hh * 64 + d];
    tbl[t] = sacc;
  }
  for (int i = t; i < 25 * 128; i += 256) {
    int c01 = i >> 7, d = i & 127;
    t01s[i] = bemb[(c01 / 5) * 128 + d] + bemb[640 + (c01 % 5) * 128 + d];
  }
  for (int i = t; i < 5 * 128; i += 256) b2s[i] = bemb[1280 + i];
  __syncthreads();
  int wave = t >> 6;
  int lane = t & 63;
  int n = blockIdx.x * 4 + wave;
  if (n >= Nn) return;
  int p0 = off[n], p1 = off[n + 1];
  float ai0 = ai[n * 2], ai1 = ai[n * 2 + 1];
  float acc0 = 0.f, acc1 = 0.f;

#define EDGE_BODY(U, HV, AJV, SDV)                                             \
  {                                                                            \
    int a0 = (U >> 17) & 7, a1 = (U >> 20) & 7, a2 = (U >> 23) & 7;            \
    float lg0 = ai0 + AJV.x + tbl[a0 * 2] + tbl[10 + a1 * 2] + tbl[20 + a2 * 2]; \
    float lg1 = ai1 + AJV.y + tbl[a0 * 2 + 1] + tbl[10 + a1 * 2 + 1] +         \
                tbl[20 + a2 * 2 + 1];                                          \
    lg0 = lg0 >= 0.f ? lg0 : NEG_SLOPE * lg0;                                  \
    lg1 = lg1 >= 0.f ? lg1 : NEG_SLOPE * lg1;                                  \
    float al0 = __expf(lg0) / (SDV.x + 1e-16f);                                \
    float al1 = __expf(lg1) / (SDV.y + 1e-16f);                                \
    int bp = (a0 * 5 + a1) * 128, b2 = a2 * 128;                               \
    float e0 = t01s[bp + lane] + b2s[b2 + lane];                               \
    float e1 = t01s[bp + 64 + lane] + b2s[b2 + 64 + lane];                     \
    acc0 += al0 * (__uint_as_float(HV << 16) + e0);                            \
    acc1 += al1 * (__uint_as_float(HV & 0xffff0000u) + e1);                    \
  }

  int p = p0;
  for (; p + 4 <= p1; p += 4) {
    unsigned u0 = eix[p], u1 = eix[p + 1], u2 = eix[p + 2], u3 = eix[p + 3];
    int r0 = u0 & 0x1FFFF, r1 = u1 & 0x1FFFF, r2 = u2 & 0x1FFFF, r3 = u3 & 0x1FFFF;
    unsigned hv0 = hb[(size_t)r0 * 64 + lane];
    unsigned hv1 = hb[(size_t)r1 * 64 + lane];
    unsigned hv2 = hb[(size_t)r2 * 64 + lane];
    unsigned hv3 = hb[(size_t)r3 * 64 + lane];
    float2 ajv0 = aj2[r0], ajv1 = aj2[r1], ajv2 = aj2[r2], ajv3 = aj2[r3];
    float2 sdv0 = sd2[r0], sdv1 = sd2[r1], sdv2 = sd2[r2], sdv3 = sd2[r3];
    EDGE_BODY(u0, hv0, ajv0, sdv0)
    EDGE_BODY(u1, hv1, ajv1, sdv1)
    EDGE_BODY(u2, hv2, ajv2, sdv2)
    EDGE_BODY(u3, hv3, ajv3, sdv3)
  }
  for (; p < p1; ++p) {
    unsigned u0 = eix[p];
    int r0 = u0 & 0x1FFFF;
    unsigned hv0 = hb[(size_t)r0 * 64 + lane];
    float2 ajv0 = aj2[r0];
    float2 sdv0 = sd2[r0];
    EDGE_BODY(u0, hv0, ajv0, sdv0)
  }
#undef EDGE_BODY
  out[(size_t)n * 64 + lane] = 0.5f * (acc0 + acc1) + bias[lane];
}

extern "C" void kernel_launch(void* const* d_in, const int* in_sizes, int n_in,
                              void* d_out, int out_size, void* d_ws, size_t ws_size,
                              hipStream_t stream) {
  const float* x    = (const float*)d_in[0];
  const int*   ei   = (const int*)d_in[1];
  const int*   eatt = (const int*)d_in[2];
  const float* W    = (const float*)d_in[3];
  const float* bW   = (const float*)d_in[4];
  const float* att  = (const float*)d_in[5];
  const float* bias = (const float*)d_in[6];
  const float* bemb = (const float*)d_in[7];
  int Nn = in_sizes[0] / 64;
  int Ee = in_sizes[1] / 2;
  int nb1 = (Nn + 255) / 256;

  char* ws = (char*)d_ws;
  ws = (char*)(((uintptr_t)ws + 15) & ~(uintptr_t)15);
  float* aj = (float*)ws;          ws += (size_t)Nn * 2 * 4;
  float* sden = (float*)ws;        ws += (size_t)Nn * 2 * 4;
  float* ai = (float*)ws;          ws += (size_t)Nn * 2 * 4;
  unsigned int* hb = (unsigned int*)ws; ws += (size_t)Nn * 64 * 4;
  int* deg = (int*)ws;             ws += (size_t)Nn * 4;
  int* wcur = (int*)ws;            ws += (size_t)Nn * 4;
  int* off = (int*)ws;             ws += (size_t)(Nn + 1) * 4;
  int* bsum = (int*)ws;            ws += (size_t)nb1 * 4;
  int* bpre = (int*)ws;            ws += (size_t)nb1 * 4;
  unsigned int* eix = (unsigned int*)ws; ws += (size_t)Ee * 4;

  hipMemsetAsync(sden, 0, (size_t)Nn * 2 * 4, stream);
  hipMemsetAsync(deg, 0, (size_t)Nn * 4, stream);
  hipMemsetAsync(wcur, 0, (size_t)Nn * 4, stream);

  k1_gemm<<<1024, 128, 0, stream>>>(x, W, bW, att, hb, ai, aj, Nn);
  k_deg<<<(Ee + 255) / 256, 256, 0, stream>>>(ei, deg, Ee);
  k_scan1<<<nb1, 256, 0, stream>>>(deg, off, bsum, Nn);
  k_scan2<<<1, 256, 0, stream>>>(bsum, bpre, nb1);
  k_scan3<<<nb1, 256, 0, stream>>>(off, bpre, Nn, Ee);
  k_fill<<<(Ee + 255) / 256, 256, 0, stream>>>(ei, eatt, att, bemb, ai, aj,
                                               sden, off, wcur, eix, Ee);
  k_gather<<<(Nn + 3) / 4, 256, 0, stream>>>(eix, off, (const float2*)aj,
                                             (const float2*)sden, ai, hb, bemb,
                                             att, bias, (float*)d_out, Nn);
}

// Round 8
// 662.378 us; speedup vs baseline: 2.3991x; 1.1136x over previous
//
#include <hip/hip_runtime.h>
#include <hip/hip_bf16.h>
#include <math.h>

#define NEG_SLOPE 0.2f
#define NPB 32          // nodes per bucket
#define MAXNB 1600      // LDS histogram capacity (NB = ceil(50000/32) = 1563)
#define BIN_CHUNK 8192  // edges per k_bin block
#define SCAP 3072       // k_sort LDS record capacity (bucket mean ~1024)

__device__ __forceinline__ unsigned f2bf(float f) {
  unsigned u = __float_as_uint(f);
  return (u + 0x7fffu + ((u >> 16) & 1u)) >> 16;  // RNE
}

// ---------------------------------------------------------------------------
// K1: h = x @ W + b_W (registers), emit:
//   hb [N][64] uint : {bf16 h(head0,d) lo | bf16 h(head1,d) hi}
//   ai [N][2], aj [N][2] : per-node attention scalars
// ---------------------------------------------------------------------------
__global__ __launch_bounds__(128) void k1_gemm(
    const float* __restrict__ x, const float* __restrict__ W,
    const float* __restrict__ bW, const float* __restrict__ att,
    unsigned int* __restrict__ hb, float* __restrict__ ai,
    float* __restrict__ aj, int Nn) {
  __shared__ float Ws[64 * 128];
  __shared__ float xs[64];
  __shared__ float bs[128];
  __shared__ float atts[256];
  __shared__ float hsh[128];
  int t = threadIdx.x;
  for (int i = t; i < 64 * 128; i += 128) Ws[i] = W[i];
  bs[t] = bW[t];
  atts[t] = att[t];
  atts[128 + t] = att[128 + t];
  __syncthreads();
  int head = t >> 6;
  int lane = t & 63;
  for (int row = blockIdx.x; row < Nn; row += gridDim.x) {
    if (t < 64) xs[t] = x[(size_t)row * 64 + t];
    __syncthreads();
    float acc = bs[t];
#pragma unroll
    for (int k = 0; k < 64; ++k) acc += xs[k] * Ws[k * 128 + t];
    hsh[t] = acc;
    float ti = atts[head * 128 + lane] * acc;
    float tj = atts[head * 128 + 64 + lane] * acc;
#pragma unroll
    for (int off = 32; off > 0; off >>= 1) {
      ti += __shfl_down(ti, off, 64);
      tj += __shfl_down(tj, off, 64);
    }
    if (lane == 0) { ai[row * 2 + head] = ti; aj[row * 2 + head] = tj; }
    __syncthreads();
    if (t < 64)
      hb[(size_t)row * 64 + t] = f2bf(hsh[t]) | (f2bf(hsh[64 + t]) << 16);
  }
}

// ---------------------------------------------------------------------------
// K_degb: per-bucket edge counts (LDS pre-aggregated histogram).
// ---------------------------------------------------------------------------
__global__ __launch_bounds__(256) void k_degb(
    const int* __restrict__ ei, int* __restrict__ bcnt, int Ee, int NB) {
  __shared__ int hist[MAXNB];
  int t = threadIdx.x;
  for (int i = t; i < NB; i += 256) hist[i] = 0;
  __syncthreads();
  int stride = gridDim.x * 256;
  for (int e = blockIdx.x * 256 + t; e < Ee; e += stride)
    atomicAdd(&hist[ei[Ee + e] >> 5], 1);
  __syncthreads();
  for (int i = t; i < NB; i += 256)
    if (hist[i]) atomicAdd(&bcnt[i], hist[i]);
}

// ---------------------------------------------------------------------------
// K_scanb: single-block exclusive scan over NB bucket counts ->
// bucketbase[NB+1] and gcursor[NB].
// ---------------------------------------------------------------------------
__global__ __launch_bounds__(256) void k_scanb(
    const int* __restrict__ bcnt, int* __restrict__ bucketbase,
    int* __restrict__ gcursor, int NB, int Ee) {
  __shared__ int s[256];
  int t = threadIdx.x;
  int per = (NB + 255) / 256;
  int local[8];
  int sum = 0;
  for (int j = 0; j < per; ++j) {
    int b = t * per + j;
    int v = (b < NB) ? bcnt[b] : 0;
    local[j] = sum;
    sum += v;
  }
  s[t] = sum;
  __syncthreads();
#pragma unroll
  for (int o = 1; o < 256; o <<= 1) {
    int xv = (t >= o) ? s[t - o] : 0;
    __syncthreads();
    s[t] += xv;
    __syncthreads();
  }
  int excl = s[t] - sum;
  for (int j = 0; j < per; ++j) {
    int b = t * per + j;
    if (b < NB) {
      int base = excl + local[j];
      bucketbase[b] = base;
      gcursor[b] = base;
    }
  }
  if (t == 0) bucketbase[NB] = Ee;
}

// ---------------------------------------------------------------------------
// K_bin: per-block LDS histogram -> per-(block,bucket) global reservation ->
// CLUSTERED record writes (runs of consecutive slots from one block, so L2
// merges them into few line writebacks — the fix for the 200 MB scatter amp).
// Record: {src:17 | dl:5<<17 | a0<<22 | a1<<25 | a2<<28}.
// Also computes softmax denominators sden[src][h] (f32 atomics, payload-sized).
// ---------------------------------------------------------------------------
__global__ __launch_bounds__(256) void k_bin(
    const int* __restrict__ ei, const int* __restrict__ eattr,
    const float* __restrict__ att, const float* __restrict__ bemb,
    const float* __restrict__ ai, const float* __restrict__ aj,
    float* __restrict__ sden, int* __restrict__ gcursor,
    unsigned int* __restrict__ rec, int Ee, int NB) {
  __shared__ int hist[MAXNB];
  __shared__ float tbl[30];
  int t = threadIdx.x;
  if (t < 30) {
    int f = t / 10, rem = t % 10, c = rem >> 1, hh = rem & 1;
    float sacc = 0.f;
    for (int d = 0; d < 64; ++d)
      sacc += att[hh * 128 + 64 + d] * bemb[(f * 5 + c) * 128 + hh * 64 + d];
    tbl[t] = sacc;
  }
  for (int i = t; i < NB; i += 256) hist[i] = 0;
  __syncthreads();
  int start = blockIdx.x * BIN_CHUNK;
  int end = min(start + BIN_CHUNK, Ee);
  for (int e = start + t; e < end; e += 256)
    atomicAdd(&hist[ei[Ee + e] >> 5], 1);
  __syncthreads();
  for (int b = t; b < NB; b += 256) {
    int c = hist[b];
    if (c) hist[b] = atomicAdd(&gcursor[b], c);
  }
  __syncthreads();
  for (int e = start + t; e < end; e += 256) {
    int dst = ei[Ee + e];
    int src = ei[e];
    int a0 = eattr[e * 3], a1 = eattr[e * 3 + 1], a2 = eattr[e * 3 + 2];
    int b = dst >> 5, dl = dst & 31;
    int pos = atomicAdd(&hist[b], 1);
    rec[pos] = (unsigned)src | ((unsigned)dl << 17) | ((unsigned)a0 << 22) |
               ((unsigned)a1 << 25) | ((unsigned)a2 << 28);
    float lg0 = ai[dst * 2] + aj[src * 2] + tbl[a0 * 2] + tbl[10 + a1 * 2] +
                tbl[20 + a2 * 2];
    float lg1 = ai[dst * 2 + 1] + aj[src * 2 + 1] + tbl[a0 * 2 + 1] +
                tbl[10 + a1 * 2 + 1] + tbl[20 + a2 * 2 + 1];
    lg0 = lg0 >= 0.f ? lg0 : NEG_SLOPE * lg0;
    lg1 = lg1 >= 0.f ? lg1 : NEG_SLOPE * lg1;
    atomicAdd(&sden[src * 2], __expf(lg0));
    atomicAdd(&sden[src * 2 + 1], __expf(lg1));
  }
}

// ---------------------------------------------------------------------------
// K_sort: one block per bucket. LDS counting sort of the bucket's records by
// dst-local id -> per-node contiguous eix2 + off[n]. All global reads/writes
// touch only the bucket's contiguous region (L2-merged, ~13 MB total).
// ---------------------------------------------------------------------------
__global__ __launch_bounds__(256) void k_sort(
    const unsigned int* __restrict__ rec, const int* __restrict__ bucketbase,
    unsigned int* __restrict__ eix2, int* __restrict__ off, int Nn, int NB) {
  __shared__ unsigned buf[SCAP];
  __shared__ int cnt[32], excl[33], cur[32];
  int t = threadIdx.x;
  int b = blockIdx.x;
  int p0 = bucketbase[b], p1 = bucketbase[b + 1];
  int ne = p1 - p0;
  if (t < 32) cnt[t] = 0;
  __syncthreads();
  bool fits = (ne <= SCAP);
  if (fits) {
    for (int p = p0 + t; p < p1; p += 256) {
      unsigned u = rec[p];
      buf[p - p0] = u;
      atomicAdd(&cnt[(u >> 17) & 31], 1);
    }
  } else {
    for (int p = p0 + t; p < p1; p += 256)
      atomicAdd(&cnt[(rec[p] >> 17) & 31], 1);
  }
  __syncthreads();
  if (t == 0) {
    int s = 0;
    for (int i = 0; i < 32; ++i) { excl[i] = s; s += cnt[i]; }
    excl[32] = s;
  }
  __syncthreads();
  if (t < 32) {
    cur[t] = excl[t];
    int n = b * NPB + t;
    if (n < Nn) off[n] = p0 + excl[t];
  }
  if (b == NB - 1 && t == 0) off[Nn] = p1;
  __syncthreads();
  if (fits) {
    for (int i = t; i < ne; i += 256) {
      unsigned u = buf[i];
      int pos = atomicAdd(&cur[(u >> 17) & 31], 1);
      eix2[p0 + pos] = u;
    }
  } else {
    for (int p = p0 + t; p < p1; p += 256) {
      unsigned u = rec[p];
      int pos = atomicAdd(&cur[(u >> 17) & 31], 1);
      eix2[p0 + pos] = u;
    }
  }
}

// ---------------------------------------------------------------------------
// K_gather: one wave per dst node (50000 independent waves — proven-good
// round-5 structure), lane = d; 8-deep unrolled edge loop with batched
// independent loads. Edge-emb via pair-combined LDS tables.
// ---------------------------------------------------------------------------
__global__ __launch_bounds__(256) void k_gather(
    const unsigned int* __restrict__ eix, const int* __restrict__ off,
    const float2* __restrict__ aj2, const float2* __restrict__ sd2,
    const float2* __restrict__ ai2, const unsigned int* __restrict__ hb,
    const float* __restrict__ bemb, const float* __restrict__ att,
    const float* __restrict__ bias, float* __restrict__ out, int Nn) {
  __shared__ float t01s[25 * 128];  // bemb0[a0]+bemb1[a1] pair table
  __shared__ float b2s[5 * 128];
  __shared__ float tbl[30];
  int t = threadIdx.x;
  if (t < 30) {
    int f = t / 10, rem = t % 10, c = rem >> 1, hh = rem & 1;
    float sacc = 0.f;
    for (int d = 0; d < 64; ++d)
      sacc += att[hh * 128 + 64 + d] * bemb[(f * 5 + c) * 128 + hh * 64 + d];
    tbl[t] = sacc;
  }
  for (int i = t; i < 25 * 128; i += 256) {
    int c01 = i >> 7, d = i & 127;
    t01s[i] = bemb[(c01 / 5) * 128 + d] + bemb[640 + (c01 % 5) * 128 + d];
  }
  for (int i = t; i < 5 * 128; i += 256) b2s[i] = bemb[1280 + i];
  __syncthreads();
  int wave = t >> 6;
  int lane = t & 63;
  int n = blockIdx.x * 4 + wave;
  if (n >= Nn) return;
  int p0 = off[n], p1 = off[n + 1];
  float2 aiv = ai2[n];
  float ai0 = aiv.x, ai1 = aiv.y;
  float acc0 = 0.f, acc1 = 0.f;

#define EDGE_BODY(U, HV, AJV, SDV)                                             \
  {                                                                            \
    int a0 = (U >> 22) & 7, a1 = (U >> 25) & 7, a2 = (U >> 28) & 7;            \
    float lg0 = ai0 + AJV.x + tbl[a0 * 2] + tbl[10 + a1 * 2] + tbl[20 + a2 * 2]; \
    float lg1 = ai1 + AJV.y + tbl[a0 * 2 + 1] + tbl[10 + a1 * 2 + 1] +         \
                tbl[20 + a2 * 2 + 1];                                          \
    lg0 = lg0 >= 0.f ? lg0 : NEG_SLOPE * lg0;                                  \
    lg1 = lg1 >= 0.f ? lg1 : NEG_SLOPE * lg1;                                  \
    float al0 = __expf(lg0) / (SDV.x + 1e-16f);                                \
    float al1 = __expf(lg1) / (SDV.y + 1e-16f);                                \
    int bp = (a0 * 5 + a1) * 128, b2i = a2 * 128;                              \
    float e0 = t01s[bp + lane] + b2s[b2i + lane];                              \
    float e1 = t01s[bp + 64 + lane] + b2s[b2i + 64 + lane];                    \
    acc0 += al0 * (__uint_as_float(HV << 16) + e0);                            \
    acc1 += al1 * (__uint_as_float(HV & 0xffff0000u) + e1);                    \
  }

  int p = p0;
  for (; p + 8 <= p1; p += 8) {
    unsigned u[8], hv[8];
    int r[8];
    float2 ajv[8], sdv[8];
#pragma unroll
    for (int k = 0; k < 8; ++k) u[k] = eix[p + k];
#pragma unroll
    for (int k = 0; k < 8; ++k) r[k] = u[k] & 0x1FFFF;
#pragma unroll
    for (int k = 0; k < 8; ++k) hv[k] = hb[(size_t)r[k] * 64 + lane];
#pragma unroll
    for (int k = 0; k < 8; ++k) ajv[k] = aj2[r[k]];
#pragma unroll
    for (int k = 0; k < 8; ++k) sdv[k] = sd2[r[k]];
#pragma unroll
    for (int k = 0; k < 8; ++k) EDGE_BODY(u[k], hv[k], ajv[k], sdv[k])
  }
  for (; p < p1; ++p) {
    unsigned u0 = eix[p];
    int r0 = u0 & 0x1FFFF;
    unsigned hv0 = hb[(size_t)r0 * 64 + lane];
    float2 ajv0 = aj2[r0];
    float2 sdv0 = sd2[r0];
    EDGE_BODY(u0, hv0, ajv0, sdv0)
  }
#undef EDGE_BODY
  out[(size_t)n * 64 + lane] = 0.5f * (acc0 + acc1) + bias[lane];
}

extern "C" void kernel_launch(void* const* d_in, const int* in_sizes, int n_in,
                              void* d_out, int out_size, void* d_ws, size_t ws_size,
                              hipStream_t stream) {
  const float* x    = (const float*)d_in[0];
  const int*   ei   = (const int*)d_in[1];
  const int*   eatt = (const int*)d_in[2];
  const float* W    = (const float*)d_in[3];
  const float* bW   = (const float*)d_in[4];
  const float* att  = (const float*)d_in[5];
  const float* bias = (const float*)d_in[6];
  const float* bemb = (const float*)d_in[7];
  int Nn = in_sizes[0] / 64;
  int Ee = in_sizes[1] / 2;
  int NB = (Nn + NPB - 1) / NPB;

  char* ws = (char*)d_ws;
  ws = (char*)(((uintptr_t)ws + 15) & ~(uintptr_t)15);
  float* aj = (float*)ws;               ws += (size_t)Nn * 2 * 4;
  float* sden = (float*)ws;             ws += (size_t)Nn * 2 * 4;
  float* ai = (float*)ws;               ws += (size_t)Nn * 2 * 4;
  unsigned int* hb = (unsigned int*)ws; ws += (size_t)Nn * 64 * 4;
  unsigned int* rec = (unsigned int*)ws;  ws += (size_t)Ee * 4;
  unsigned int* eix2 = (unsigned int*)ws; ws += (size_t)Ee * 4;
  int* off = (int*)ws;                  ws += (size_t)(Nn + 1) * 4;
  int* bcnt = (int*)ws;                 ws += (size_t)NB * 4;
  int* bucketbase = (int*)ws;           ws += (size_t)(NB + 1) * 4;
  int* gcursor = (int*)ws;              ws += (size_t)NB * 4;

  hipMemsetAsync(sden, 0, (size_t)Nn * 2 * 4, stream);
  hipMemsetAsync(bcnt, 0, (size_t)NB * 4, stream);

  k1_gemm<<<1024, 128, 0, stream>>>(x, W, bW, att, hb, ai, aj, Nn);
  k_degb<<<512, 256, 0, stream>>>(ei, bcnt, Ee, NB);
  k_scanb<<<1, 256, 0, stream>>>(bcnt, bucketbase, gcursor, NB, Ee);
  k_bin<<<(Ee + BIN_CHUNK - 1) / BIN_CHUNK, 256, 0, stream>>>(
      ei, eatt, att, bemb, ai, aj, sden, gcursor, rec, Ee, NB);
  k_sort<<<NB, 256, 0, stream>>>(rec, bucketbase, eix2, off, Nn, NB);
  k_gather<<<(Nn + 3) / 4, 256, 0, stream>>>(eix2, off, (const float2*)aj,
                                             (const float2*)sden,
                                             (const float2*)ai, hb, bemb, att,
                                             bias, (float*)d_out, Nn);
}

// Round 9
// 486.196 us; speedup vs baseline: 3.2685x; 1.3624x over previous
//
#include <hip/hip_runtime.h>
#include <hip/hip_bf16.h>
#include <math.h>

#define NEG_SLOPE 0.2f
#define NPB 32          // nodes per bucket
#define MAXNB 1600      // LDS histogram capacity (NB = ceil(50000/32) = 1563)
#define BIN_CHUNK 8192  // edges per k_bin block

__device__ __forceinline__ unsigned f2bf(float f) {
  unsigned u = __float_as_uint(f);
  return (u + 0x7fffu + ((u >> 16) & 1u)) >> 16;  // RNE
}

// ---------------------------------------------------------------------------
// K1: h = x @ W + b_W (registers), emit:
//   hb [N][64] uint : {bf16 h(head0,d) lo | bf16 h(head1,d) hi}
//   ai [N][2], aj [N][2] : per-node attention scalars
// ---------------------------------------------------------------------------
__global__ __launch_bounds__(128) void k1_gemm(
    const float* __restrict__ x, const float* __restrict__ W,
    const float* __restrict__ bW, const float* __restrict__ att,
    unsigned int* __restrict__ hb, float* __restrict__ ai,
    float* __restrict__ aj, int Nn) {
  __shared__ float Ws[64 * 128];
  __shared__ float xs[64];
  __shared__ float bs[128];
  __shared__ float atts[256];
  __shared__ float hsh[128];
  int t = threadIdx.x;
  for (int i = t; i < 64 * 128; i += 128) Ws[i] = W[i];
  bs[t] = bW[t];
  atts[t] = att[t];
  atts[128 + t] = att[128 + t];
  __syncthreads();
  int head = t >> 6;
  int lane = t & 63;
  for (int row = blockIdx.x; row < Nn; row += gridDim.x) {
    if (t < 64) xs[t] = x[(size_t)row * 64 + t];
    __syncthreads();
    float acc = bs[t];
#pragma unroll
    for (int k = 0; k < 64; ++k) acc += xs[k] * Ws[k * 128 + t];
    hsh[t] = acc;
    float ti = atts[head * 128 + lane] * acc;
    float tj = atts[head * 128 + 64 + lane] * acc;
#pragma unroll
    for (int off = 32; off > 0; off >>= 1) {
      ti += __shfl_down(ti, off, 64);
      tj += __shfl_down(tj, off, 64);
    }
    if (lane == 0) { ai[row * 2 + head] = ti; aj[row * 2 + head] = tj; }
    __syncthreads();
    if (t < 64)
      hb[(size_t)row * 64 + t] = f2bf(hsh[t]) | (f2bf(hsh[64 + t]) << 16);
  }
}

// ---------------------------------------------------------------------------
// K_degb: per-bucket edge counts (LDS pre-aggregated histogram).
// ---------------------------------------------------------------------------
__global__ __launch_bounds__(256) void k_degb(
    const int* __restrict__ ei, int* __restrict__ bcnt, int Ee, int NB) {
  __shared__ int hist[MAXNB];
  int t = threadIdx.x;
  for (int i = t; i < NB; i += 256) hist[i] = 0;
  __syncthreads();
  int stride = gridDim.x * 256;
  for (int e = blockIdx.x * 256 + t; e < Ee; e += stride)
    atomicAdd(&hist[ei[Ee + e] >> 5], 1);
  __syncthreads();
  for (int i = t; i < NB; i += 256)
    if (hist[i]) atomicAdd(&bcnt[i], hist[i]);
}

// ---------------------------------------------------------------------------
// K_scanb: single-block exclusive scan over NB bucket counts.
// ---------------------------------------------------------------------------
__global__ __launch_bounds__(256) void k_scanb(
    const int* __restrict__ bcnt, int* __restrict__ bucketbase,
    int* __restrict__ gcursor, int NB, int Ee) {
  __shared__ int s[256];
  int t = threadIdx.x;
  int per = (NB + 255) / 256;
  int local[8];
  int sum = 0;
  for (int j = 0; j < per; ++j) {
    int b = t * per + j;
    int v = (b < NB) ? bcnt[b] : 0;
    local[j] = sum;
    sum += v;
  }
  s[t] = sum;
  __syncthreads();
#pragma unroll
  for (int o = 1; o < 256; o <<= 1) {
    int xv = (t >= o) ? s[t - o] : 0;
    __syncthreads();
    s[t] += xv;
    __syncthreads();
  }
  int excl = s[t] - sum;
  for (int j = 0; j < per; ++j) {
    int b = t * per + j;
    if (b < NB) {
      int base = excl + local[j];
      bucketbase[b] = base;
      gcursor[b] = base;
    }
  }
  if (t == 0) bucketbase[NB] = Ee;
}

// ---------------------------------------------------------------------------
// K_bin: per-block LDS histogram -> per-(block,bucket) reservation ->
// CLUSTERED writes of rec {src:17 | dl:5<<17 | a0<<22 | a1<<25 | a2<<28} and
// rec2 {exp(lg0), exp(lg1)}. Softmax denominators via f32 atomics.
// ---------------------------------------------------------------------------
__global__ __launch_bounds__(256) void k_bin(
    const int* __restrict__ ei, const int* __restrict__ eattr,
    const float* __restrict__ att, const float* __restrict__ bemb,
    const float* __restrict__ ai, const float* __restrict__ aj,
    float* __restrict__ sden, int* __restrict__ gcursor,
    unsigned int* __restrict__ rec, float2* __restrict__ rec2, int Ee, int NB) {
  __shared__ int hist[MAXNB];
  __shared__ float tbl[30];
  int t = threadIdx.x;
  if (t < 30) {
    int f = t / 10, rem = t % 10, c = rem >> 1, hh = rem & 1;
    float sacc = 0.f;
    for (int d = 0; d < 64; ++d)
      sacc += att[hh * 128 + 64 + d] * bemb[(f * 5 + c) * 128 + hh * 64 + d];
    tbl[t] = sacc;
  }
  for (int i = t; i < NB; i += 256) hist[i] = 0;
  __syncthreads();
  int start = blockIdx.x * BIN_CHUNK;
  int end = min(start + BIN_CHUNK, Ee);
  for (int e = start + t; e < end; e += 256)
    atomicAdd(&hist[ei[Ee + e] >> 5], 1);
  __syncthreads();
  for (int b = t; b < NB; b += 256) {
    int c = hist[b];
    if (c) hist[b] = atomicAdd(&gcursor[b], c);
  }
  __syncthreads();
  for (int e = start + t; e < end; e += 256) {
    int dst = ei[Ee + e];
    int src = ei[e];
    int a0 = eattr[e * 3], a1 = eattr[e * 3 + 1], a2 = eattr[e * 3 + 2];
    int b = dst >> 5, dl = dst & 31;
    float lg0 = ai[dst * 2] + aj[src * 2] + tbl[a0 * 2] + tbl[10 + a1 * 2] +
                tbl[20 + a2 * 2];
    float lg1 = ai[dst * 2 + 1] + aj[src * 2 + 1] + tbl[a0 * 2 + 1] +
                tbl[10 + a1 * 2 + 1] + tbl[20 + a2 * 2 + 1];
    lg0 = lg0 >= 0.f ? lg0 : NEG_SLOPE * lg0;
    lg1 = lg1 >= 0.f ? lg1 : NEG_SLOPE * lg1;
    float e0 = __expf(lg0), e1 = __expf(lg1);
    atomicAdd(&sden[src * 2], e0);
    atomicAdd(&sden[src * 2 + 1], e1);
    int pos = atomicAdd(&hist[b], 1);
    rec[pos] = (unsigned)src | ((unsigned)dl << 17) | ((unsigned)a0 << 22) |
               ((unsigned)a1 << 25) | ((unsigned)a2 << 28);
    rec2[pos] = make_float2(e0, e1);
  }
}

// ---------------------------------------------------------------------------
// K_sort: one block per bucket. Counting sort by dst-local id; emits the
// per-node CSR (eix2, off) plus FINISHED attention weights
// alpha2[p] = exp(lg)/sden[src] so the gather does zero scalar recompute.
// All global I/O confined to the bucket's contiguous region (L2-merged).
// ---------------------------------------------------------------------------
__global__ __launch_bounds__(256) void k_sort(
    const unsigned int* __restrict__ rec, const float2* __restrict__ rec2,
    const int* __restrict__ bucketbase, const float2* __restrict__ sd2,
    unsigned int* __restrict__ eix2, float2* __restrict__ alpha2,
    int* __restrict__ off, int Nn, int NB) {
  __shared__ int cnt[32], excl[32], cur[32];
  int t = threadIdx.x, b = blockIdx.x;
  int p0 = bucketbase[b], p1 = bucketbase[b + 1];
  if (t < 32) cnt[t] = 0;
  __syncthreads();
  for (int p = p0 + t; p < p1; p += 256)
    atomicAdd(&cnt[(rec[p] >> 17) & 31], 1);
  __syncthreads();
  if (t == 0) {
    int s = 0;
    for (int i = 0; i < 32; ++i) { excl[i] = s; s += cnt[i]; }
  }
  __syncthreads();
  if (t < 32) {
    cur[t] = excl[t];
    int n = b * NPB + t;
    if (n < Nn) off[n] = p0 + excl[t];
  }
  if (b == NB - 1 && t == 0) off[Nn] = p1;
  __syncthreads();
  for (int p = p0 + t; p < p1; p += 256) {
    unsigned u = rec[p];
    float2 ea = rec2[p];
    int src = u & 0x1FFFF;
    float2 sd = sd2[src];
    int pos = atomicAdd(&cur[(u >> 17) & 31], 1);
    eix2[p0 + pos] = u;
    alpha2[p0 + pos] =
        make_float2(ea.x / (sd.x + 1e-16f), ea.y / (sd.y + 1e-16f));
  }
}

// ---------------------------------------------------------------------------
// K_gather: one wave per dst node, lane = d. Per edge: sequential rec+alpha
// reads, one coalesced hb gather, 2 FMA + predicated w-update. Edge-emb term
// hoisted algebraically: lanes 0..29 accumulate w[f,c,h] = sum(alpha) over
// matching edges; epilogue adds sum_k w_k * bemb_k (15-term weighted sum).
// ---------------------------------------------------------------------------
__global__ __launch_bounds__(256) void k_gather(
    const unsigned int* __restrict__ eix, const float2* __restrict__ alpha2,
    const int* __restrict__ off, const unsigned int* __restrict__ hb,
    const float* __restrict__ bemb, const float* __restrict__ bias,
    float* __restrict__ out, int Nn) {
  __shared__ float bembs[15 * 128];  // [f*5+c][128]
  __shared__ float wsm[4][32];
  int t = threadIdx.x;
  for (int i = t; i < 15 * 128; i += 256) bembs[i] = bemb[i];
  __syncthreads();
  int wave = t >> 6, lane = t & 63;
  int n = blockIdx.x * 4 + wave;
  if (n >= Nn) return;
  int p0 = off[n], p1 = off[n + 1];
  // lane < 30 holds w for (f = lane/10, c = (lane%10)>>1, h = lane&1)
  int myf = lane / 10;
  int myc = (lane % 10) >> 1;
  bool myh = (lane & 1) != 0;
  bool active = lane < 30;
  float w = 0.f;
  float acc0 = 0.f, acc1 = 0.f;

#define EDGE_BODY(U, HV, AL)                                                   \
  {                                                                            \
    acc0 += AL.x * __uint_as_float(HV << 16);                                  \
    acc1 += AL.y * __uint_as_float(HV & 0xffff0000u);                          \
    int a0 = (U >> 22) & 7, a1 = (U >> 25) & 7, a2 = (U >> 28) & 7;            \
    int sel = myf == 0 ? a0 : (myf == 1 ? a1 : a2);                            \
    w += (active && myc == sel) ? (myh ? AL.y : AL.x) : 0.f;                   \
  }

  int p = p0;
  for (; p + 8 <= p1; p += 8) {
    unsigned u[8], hv[8];
    float2 al[8];
#pragma unroll
    for (int k = 0; k < 8; ++k) u[k] = eix[p + k];
#pragma unroll
    for (int k = 0; k < 8; ++k) al[k] = alpha2[p + k];
#pragma unroll
    for (int k = 0; k < 8; ++k)
      hv[k] = hb[(size_t)(u[k] & 0x1FFFF) * 64 + lane];
#pragma unroll
    for (int k = 0; k < 8; ++k) EDGE_BODY(u[k], hv[k], al[k])
  }
  for (; p < p1; ++p) {
    unsigned u0 = eix[p];
    float2 al0 = alpha2[p];
    unsigned hv0 = hb[(size_t)(u0 & 0x1FFFF) * 64 + lane];
    EDGE_BODY(u0, hv0, al0)
  }
#undef EDGE_BODY

  if (active) wsm[wave][lane] = w;  // same-wave LDS ops are in-order
#pragma unroll
  for (int k = 0; k < 15; ++k) {
    acc0 += wsm[wave][k * 2] * bembs[k * 128 + lane];
    acc1 += wsm[wave][k * 2 + 1] * bembs[k * 128 + 64 + lane];
  }
  out[(size_t)n * 64 + lane] = 0.5f * (acc0 + acc1) + bias[lane];
}

extern "C" void kernel_launch(void* const* d_in, const int* in_sizes, int n_in,
                              void* d_out, int out_size, void* d_ws, size_t ws_size,
                              hipStream_t stream) {
  const float* x    = (const float*)d_in[0];
  const int*   ei   = (const int*)d_in[1];
  const int*   eatt = (const int*)d_in[2];
  const float* W    = (const float*)d_in[3];
  const float* bW   = (const float*)d_in[4];
  const float* att  = (const float*)d_in[5];
  const float* bias = (const float*)d_in[6];
  const float* bemb = (const float*)d_in[7];
  int Nn = in_sizes[0] / 64;
  int Ee = in_sizes[1] / 2;
  int NB = (Nn + NPB - 1) / NPB;

  char* ws = (char*)d_ws;
  ws = (char*)(((uintptr_t)ws + 15) & ~(uintptr_t)15);
  float* aj = (float*)ws;                ws += (size_t)Nn * 2 * 4;
  float* sden = (float*)ws;              ws += (size_t)Nn * 2 * 4;
  float* ai = (float*)ws;                ws += (size_t)Nn * 2 * 4;
  unsigned int* hb = (unsigned int*)ws;  ws += (size_t)Nn * 64 * 4;
  unsigned int* rec = (unsigned int*)ws; ws += (size_t)Ee * 4;
  float2* rec2 = (float2*)ws;            ws += (size_t)Ee * 8;
  unsigned int* eix2 = (unsigned int*)ws; ws += (size_t)Ee * 4;
  float2* alpha2 = (float2*)ws;          ws += (size_t)Ee * 8;
  int* off = (int*)ws;                   ws += (size_t)(Nn + 1) * 4;
  int* bcnt = (int*)ws;                  ws += (size_t)NB * 4;
  int* bucketbase = (int*)ws;            ws += (size_t)(NB + 1) * 4;
  int* gcursor = (int*)ws;               ws += (size_t)NB * 4;

  hipMemsetAsync(sden, 0, (size_t)Nn * 2 * 4, stream);
  hipMemsetAsync(bcnt, 0, (size_t)NB * 4, stream);

  k1_gemm<<<1024, 128, 0, stream>>>(x, W, bW, att, hb, ai, aj, Nn);
  k_degb<<<512, 256, 0, stream>>>(ei, bcnt, Ee, NB);
  k_scanb<<<1, 256, 0, stream>>>(bcnt, bucketbase, gcursor, NB, Ee);
  k_bin<<<(Ee + BIN_CHUNK - 1) / BIN_CHUNK, 256, 0, stream>>>(
      ei, eatt, att, bemb, ai, aj, sden, gcursor, rec, rec2, Ee, NB);
  k_sort<<<NB, 256, 0, stream>>>(rec, rec2, bucketbase, (const float2*)sden,
                                 eix2, alpha2, off, Nn, NB);
  k_gather<<<(Nn + 3) / 4, 256, 0, stream>>>(eix2, alpha2, off, hb, bemb, bias,
                                             (float*)d_out, Nn);
}